// Round 4
// baseline (9086.230 us; speedup 1.0000x reference)
//
#include <hip/hip_runtime.h>
#include <hip/hip_bf16.h>
#include <math.h>

#define BB 1024
#define TT 64
#define OBSN 64
#define ACTN 8
#define STOCHN 32
#define DETERN 512
#define HIDN 512
#define G3N 1536
#define CATPI 40
#define OUTC 672
#define LNEPS 1e-3f
#define MINSTD 0.1f
#define UPDBIAS -1.0f
#define NBLK 256

typedef __attribute__((ext_vector_type(8))) short short8;
typedef __attribute__((ext_vector_type(4))) short short4v;
typedef __attribute__((ext_vector_type(4))) float f32x4;

__device__ __forceinline__ float sigmoidf_(float x) { return 1.f / (1.f + expf(-x)); }
__device__ __forceinline__ float siluf_(float x) { return x / (1.f + expf(-x)); }
__device__ __forceinline__ float softplusf_(float x) { return (x > 20.f) ? x : log1pf(expf(x)); }

__device__ __forceinline__ float b2f(short u) {
    unsigned x = ((unsigned)(unsigned short)u) << 16;
    return __builtin_bit_cast(float, x);
}
__device__ __forceinline__ short f2b(float f) {
    __hip_bfloat16 h = __float2bfloat16(f);
    return __builtin_bit_cast(short, h);
}

__device__ __forceinline__ void gload_lds16(const void* g, void* l) {
    __builtin_amdgcn_global_load_lds((const __attribute__((address_space(1))) void*)g,
                                     (__attribute__((address_space(3))) void*)l, 16, 0, 0);
}

__device__ __forceinline__ void wred2(float& a, float& b) {
#pragma unroll
    for (int off = 32; off; off >>= 1) {
        a += __shfl_xor(a, off);
        b += __shfl_xor(b, off);
    }
}
__device__ __forceinline__ void wred4(float& a, float& b, float& c, float& d) {
#pragma unroll
    for (int off = 32; off; off >>= 1) {
        a += __shfl_xor(a, off);
        b += __shfl_xor(b, off);
        c += __shfl_xor(c, off);
        d += __shfl_xor(d, off);
    }
}

// ---- grid barrier: plain persistent grid (256 blocks <= 256 CUs, co-resident by construction).
// __syncthreads drains all waves' stores (vmcnt 0 before s_barrier); thread-0 release fence
// writes back the XCD L2; acquire fence invalidates before anyone proceeds.
__device__ __forceinline__ void gbar(unsigned* cnt, unsigned& gen) {
    __syncthreads();
    gen += NBLK;
    if (threadIdx.x == 0) {
        __threadfence();  // release: L2 writeback (agent scope)
        __hip_atomic_fetch_add(cnt, 1u, __ATOMIC_RELAXED, __HIP_MEMORY_SCOPE_AGENT);
        while (__hip_atomic_load(cnt, __ATOMIC_RELAXED, __HIP_MEMORY_SCOPE_AGENT) < gen)
            __builtin_amdgcn_s_sleep(2);
        __threadfence();  // acquire: L1/L2 invalidate (agent scope)
    }
    __syncthreads();
}

// ---- block-wide reduction (init phase only) ----
template <int NV>
__device__ __forceinline__ void breduce(float* v, float* red, int nwaves) {
    __syncthreads();
#pragma unroll
    for (int off = 32; off > 0; off >>= 1)
#pragma unroll
        for (int q = 0; q < NV; ++q) v[q] += __shfl_down(v[q], off);
    int lane = threadIdx.x & 63, w = threadIdx.x >> 6;
    if (lane == 0)
        for (int q = 0; q < NV; ++q) red[w * NV + q] = v[q];
    __syncthreads();
    if ((int)threadIdx.x < NV) {
        float s = 0.f;
        for (int ww = 0; ww < nwaves; ++ww) s += red[ww * NV + threadIdx.x];
        red[nwaves * NV + threadIdx.x] = s;
    }
    __syncthreads();
#pragma unroll
    for (int q = 0; q < NV; ++q) v[q] = red[nwaves * NV + q];
}

// ==== double-buffered MFMA tile core. BM=64, BN=32*NFC, BK=64. 4 waves 2x2. ====
template <int NFC>
__device__ __forceinline__ void stage_tile(const __hip_bfloat16* A0, int ld0, int K0, const __hip_bfloat16* A1,
                                           int ld1, const __hip_bfloat16* Wt, int ldW, int wn0, int cm0, int k0,
                                           char* smA, char* smB) {
    int tid = threadIdx.x, wid = tid >> 6, lane = tid & 63;
    int rseg = lane >> 3, slot = lane & 7;
    const __hip_bfloat16* Ab;
    int ldA, kloc;
    if (k0 < K0) {
        Ab = A0; ldA = ld0; kloc = k0;
    } else {
        Ab = A1; ldA = ld1; kloc = k0 - K0;
    }
#pragma unroll
    for (int i = 0; i < 2; ++i) {
        int seg = wid * 2 + i;
        int row = seg * 8 + rseg;
        int kk = kloc + ((slot ^ (row & 7)) << 3);
        gload_lds16(Ab + (size_t)(cm0 + row) * ldA + kk, smA + seg * 1024);
    }
#pragma unroll
    for (int i = 0; i < NFC; ++i) {
        int seg = wid * NFC + i;
        int row = seg * 8 + rseg;
        int kk = k0 + ((slot ^ (row & 7)) << 3);
        gload_lds16(Wt + (size_t)(wn0 + row) * ldW + kk, smB + seg * 1024);
    }
}

template <int NFC>
__device__ __forceinline__ void compute_tile(const char* smA, const char* smB, f32x4 (&acc)[2][NFC]) {
    int lane = threadIdx.x & 63, wid = threadIdx.x >> 6;
    int wr = wid >> 1, wc = wid & 1;
#pragma unroll
    for (int ks = 0; ks < 2; ++ks) {
        short8 af[2], bfr[NFC];
        int kslot = ks * 4 + (lane >> 4);
#pragma unroll
        for (int m = 0; m < 2; ++m) {
            int row = wr * 32 + m * 16 + (lane & 15);
            af[m] = *(const short8*)(smA + row * 128 + ((kslot ^ (row & 7)) << 4));
        }
#pragma unroll
        for (int n = 0; n < NFC; ++n) {
            int row = wc * (16 * NFC) + n * 16 + (lane & 15);
            bfr[n] = *(const short8*)(smB + row * 128 + ((kslot ^ (row & 7)) << 4));
        }
#pragma unroll
        for (int m = 0; m < 2; ++m)
#pragma unroll
            for (int n = 0; n < NFC; ++n)
                acc[m][n] = __builtin_amdgcn_mfma_f32_16x16x32_bf16(af[m], bfr[n], acc[m][n], 0, 0, 0);
    }
}

template <int NFC>
__device__ __forceinline__ void gemm_tile_db(const __hip_bfloat16* A0, int ld0, int K0, const __hip_bfloat16* A1,
                                             int ld1, const __hip_bfloat16* Wt, int ldW, int wn0, float* C, int ldc,
                                             int cm0, int cn0, int nK, char* smem) {
    char* smA[2] = {smem, smem + 8192};
    char* smB[2] = {smem + 16384, smem + 16384 + NFC * 4096};
    f32x4 acc[2][NFC] = {};
    stage_tile<NFC>(A0, ld0, K0, A1, ld1, Wt, ldW, wn0, cm0, 0, smA[0], smB[0]);
    for (int kt = 0; kt < nK; ++kt) {
        if (kt + 1 < nK) {
            stage_tile<NFC>(A0, ld0, K0, A1, ld1, Wt, ldW, wn0, cm0, (kt + 1) * 64, smA[(kt + 1) & 1],
                            smB[(kt + 1) & 1]);
            if constexpr (NFC == 4) asm volatile("s_waitcnt vmcnt(6)" ::: "memory");
            else if constexpr (NFC == 3) asm volatile("s_waitcnt vmcnt(5)" ::: "memory");
            else asm volatile("s_waitcnt vmcnt(4)" ::: "memory");
        } else {
            asm volatile("s_waitcnt vmcnt(0)" ::: "memory");
        }
        __builtin_amdgcn_s_barrier();
        compute_tile<NFC>(smA[kt & 1], smB[kt & 1], acc);
        __builtin_amdgcn_s_barrier();
    }
    int lane = threadIdx.x & 63, wid = threadIdx.x >> 6;
    int wr = wid >> 1, wc = wid & 1;
    int r0 = cm0 + wr * 32 + (lane >> 4) * 4;
    int c0 = cn0 + wc * 16 * NFC + (lane & 15);
#pragma unroll
    for (int m = 0; m < 2; ++m)
#pragma unroll
        for (int n = 0; n < NFC; ++n)
#pragma unroll
            for (int i = 0; i < 4; ++i)
                C[(size_t)(r0 + m * 16 + i) * ldc + c0 + n * 16] = acc[m][n][i];
}

// ---- init: dinit = tanh(init_deter); sinit = prior mean at dinit (block 0 only) ----
__device__ void phase_init(const float* init_deter, const float* W_po, const float* g_po, const float* b_po,
                           const float* W_ps, const float* b_ps, float* dinit, float* sinit, float* smemf,
                           float* red) {
    float* d_s = smemf;
    float* h_s = smemf + 512;
    int tid = threadIdx.x;
    float o[2];
#pragma unroll
    for (int s = 0; s < 2; ++s) {
        int j = tid + s * 256;
        float dv = tanhf(init_deter[j]);
        d_s[j] = dv;
        dinit[j] = dv;
    }
    __syncthreads();
#pragma unroll
    for (int s = 0; s < 2; ++s) {
        int j = tid + s * 256;
        float acc = 0.f;
        for (int k = 0; k < 512; ++k) acc += d_s[k] * W_po[k * 512 + j];
        o[s] = acc;
    }
    float v[2] = {o[0] + o[1], o[0] * o[0] + o[1] * o[1]};
    breduce<2>(v, red, 4);
    float m = v[0] / 512.f, va = v[1] / 512.f - m * m, iv = rsqrtf(va + LNEPS);
#pragma unroll
    for (int s = 0; s < 2; ++s) {
        int j = tid + s * 256;
        h_s[j] = siluf_((o[s] - m) * iv * g_po[j] + b_po[j]);
    }
    __syncthreads();
    if (tid < 32) {
        float acc = b_ps[tid];
        for (int k = 0; k < 512; ++k) acc += h_s[k] * W_ps[k * 64 + tid];
        sinit[tid] = acc;
    }
}

// ---- shared prior_in row routine: x = silu(LN(a_s @ W_pi)) -> xbf ----
__device__ __forceinline__ void prior_in_row(int row, int l, const float* a_s, const __hip_bfloat16* Wpibf,
                                             const float* g_pi, const float* b_pi, __hip_bfloat16* xbf) {
    int j0 = l * 8;
    float o[8] = {0.f, 0.f, 0.f, 0.f, 0.f, 0.f, 0.f, 0.f};
    for (int k = 0; k < CATPI; ++k) {
        float a = a_s[k];
        short8 w8 = *(const short8*)(Wpibf + k * 512 + j0);
#pragma unroll
        for (int e = 0; e < 8; ++e) o[e] += a * b2f(w8[e]);
    }
    float s = 0.f, sq = 0.f;
#pragma unroll
    for (int e = 0; e < 8; ++e) {
        s += o[e];
        sq += o[e] * o[e];
    }
    wred2(s, sq);
    float m = s * (1.f / 512.f), iv = rsqrtf(sq * (1.f / 512.f) - m * m + LNEPS);
    short8 xo;
#pragma unroll
    for (int e = 0; e < 8; ++e) {
        float x = siluf_((o[e] - m) * iv * g_pi[j0 + e] + b_pi[j0 + e]);
        xo[e] = f2b(x);
    }
    *(short8*)(xbf + (size_t)row * 512 + j0) = xo;
}

// ---- t=0: state init + prior_in ----
__device__ void phase_prior0(const int* isf, const float* action, const float* sinit, const float* dinit,
                             float* deter, __hip_bfloat16* dbf, const __hip_bfloat16* Wpibf, const float* g_pi,
                             const float* b_pi, __hip_bfloat16* xbf, float* aux) {
    int w = threadIdx.x >> 6, l = threadIdx.x & 63;
    int row = blockIdx.x * 4 + w;
    float* a_s = aux + w * 40;
    int first = isf[row * TT] > 0;
    if (l < CATPI) a_s[l] = (l < STOCHN) ? sinit[l] : (first ? 0.f : action[(size_t)row * TT * ACTN + (l - 32)]);
    int j0 = l * 8;
    float dv[8];
    *(f32x4*)&dv[0] = *(const f32x4*)(dinit + j0);
    *(f32x4*)&dv[4] = *(const f32x4*)(dinit + j0 + 4);
    *(f32x4*)(deter + (size_t)row * 512 + j0) = *(const f32x4*)&dv[0];
    *(f32x4*)(deter + (size_t)row * 512 + j0 + 4) = *(const f32x4*)&dv[4];
    short8 db;
#pragma unroll
    for (int e = 0; e < 8; ++e) db[e] = f2b(dv[e]);
    *(short8*)(dbf + (size_t)row * 512 + j0) = db;
    prior_in_row(row, l, a_s, Wpibf, g_pi, b_pi, xbf);
}

// ---- P2: LN(gates) + GRU update -> deter_n (wave per row, 4 rows/block) ----
__device__ void p2_update(int t, const float* gates, const float* g_gru, const float* b_gru, float* deter,
                          __hip_bfloat16* dbf, float* out) {
    int w = threadIdx.x >> 6, l = threadIdx.x & 63;
    int row = blockIdx.x * 4 + w;
    const float* gr = gates + (size_t)row * G3N;
    float gv[6][4];
    float s = 0.f, sq = 0.f;
#pragma unroll
    for (int i = 0; i < 6; ++i) {
        f32x4 v = *(const f32x4*)(gr + i * 256 + l * 4);
#pragma unroll
        for (int c = 0; c < 4; ++c) {
            gv[i][c] = v[c];
            s += v[c];
            sq += v[c] * v[c];
        }
    }
    wred2(s, sq);
    float m = s * (1.f / 1536.f), iv = rsqrtf(sq * (1.f / 1536.f) - m * m + LNEPS);
    size_t obase = ((size_t)row * TT + t) * OUTC + 160;
#pragma unroll
    for (int i = 0; i < 2; ++i) {
        int j = i * 256 + l * 4;
        f32x4 grr = *(const f32x4*)(g_gru + j), brr = *(const f32x4*)(b_gru + j);
        f32x4 gcc = *(const f32x4*)(g_gru + 512 + j), bcc = *(const f32x4*)(b_gru + 512 + j);
        f32x4 guu = *(const f32x4*)(g_gru + 1024 + j), buu = *(const f32x4*)(b_gru + 1024 + j);
        f32x4 dp = *(const f32x4*)(deter + (size_t)row * 512 + j);
        f32x4 dn;
        short4v db;
#pragma unroll
        for (int c = 0; c < 4; ++c) {
            float rv = sigmoidf_((gv[i][c] - m) * iv * grr[c] + brr[c]);
            float cv = (gv[i + 2][c] - m) * iv * gcc[c] + bcc[c];
            float uv = sigmoidf_((gv[i + 4][c] - m) * iv * guu[c] + buu[c] + UPDBIAS);
            float cand = siluf_(rv * cv);
            dn[c] = uv * cand + (1.f - uv) * dp[c];
            db[c] = f2b(dn[c]);
        }
        *(f32x4*)(deter + (size_t)row * 512 + j) = dn;
        *(f32x4*)(out + obase + j) = dn;
        *(short4v*)(dbf + (size_t)row * 512 + j) = db;
    }
}

// ---- P4: LN+silu hp/hq, stats dots, outputs, next-step prior_in ----
__device__ void p4_stats(int t, const float* hbuf, const float* g_po, const float* b_po, const float* g_pn,
                         const float* b_pn, const __hip_bfloat16* WpsT, const float* b_ps,
                         const __hip_bfloat16* WptT, const float* b_pt, const int* isf, const float* action,
                         const float* sinit, const float* dinit, float* deter, __hip_bfloat16* dbf,
                         const __hip_bfloat16* Wpibf, const float* g_pi, const float* b_pi,
                         __hip_bfloat16* xbf, float* out, float* smemf, float* aux) {
    int w = threadIdx.x >> 6, l = threadIdx.x & 63;
    int row = blockIdx.x * 4 + w;
    float* hp_s = smemf + w * 512;
    float* hq_s = smemf + 2048 + w * 512;
    const float* hrow = hbuf + (size_t)row * 1024;
    int j0 = l * 8;
    float hp[8], hq[8];
    *(f32x4*)&hp[0] = *(const f32x4*)(hrow + j0);
    *(f32x4*)&hp[4] = *(const f32x4*)(hrow + j0 + 4);
    *(f32x4*)&hq[0] = *(const f32x4*)(hrow + 512 + j0);
    *(f32x4*)&hq[4] = *(const f32x4*)(hrow + 512 + j0 + 4);
    float sp = 0.f, spq = 0.f, sh = 0.f, shq = 0.f;
#pragma unroll
    for (int e = 0; e < 8; ++e) {
        sp += hp[e];
        spq += hp[e] * hp[e];
        sh += hq[e];
        shq += hq[e] * hq[e];
    }
    wred4(sp, spq, sh, shq);
    float mp = sp * (1.f / 512.f), ip = rsqrtf(spq * (1.f / 512.f) - mp * mp + LNEPS);
    float mq = sh * (1.f / 512.f), iq = rsqrtf(shq * (1.f / 512.f) - mq * mq + LNEPS);
#pragma unroll
    for (int e = 0; e < 8; ++e) {
        hp[e] = siluf_((hp[e] - mp) * ip * g_po[j0 + e] + b_po[j0 + e]);
        hq[e] = siluf_((hq[e] - mq) * iq * g_pn[j0 + e] + b_pn[j0 + e]);
    }
    *(f32x4*)&hp_s[j0] = *(const f32x4*)&hp[0];
    *(f32x4*)&hp_s[j0 + 4] = *(const f32x4*)&hp[4];
    *(f32x4*)&hq_s[j0] = *(const f32x4*)&hq[0];
    *(f32x4*)&hq_s[j0 + 4] = *(const f32x4*)&hq[4];
    // stats dots: lane l computes ps[l] (from hp) and qs[l] (from hq)
    float accp = b_ps[l], accq = b_pt[l];
    const __hip_bfloat16* wpr = WpsT + (size_t)l * 512;
    const __hip_bfloat16* wqr = WptT + (size_t)l * 512;
    for (int k0 = 0; k0 < 512; k0 += 8) {
        short8 wp = *(const short8*)(wpr + k0);
        short8 wq = *(const short8*)(wqr + k0);
        float a[8], c[8];
        *(f32x4*)&a[0] = *(const f32x4*)&hp_s[k0];
        *(f32x4*)&a[4] = *(const f32x4*)&hp_s[k0 + 4];
        *(f32x4*)&c[0] = *(const f32x4*)&hq_s[k0];
        *(f32x4*)&c[4] = *(const f32x4*)&hq_s[k0 + 4];
#pragma unroll
        for (int e = 0; e < 8; ++e) {
            accp += b2f(wp[e]) * a[e];
            accq += b2f(wq[e]) * c[e];
        }
    }
    size_t base = ((size_t)row * TT + t) * OUTC;
    if (l < 32) {
        out[base + l] = accq;
        out[base + 64 + l] = accq;
        out[base + 96 + l] = accp;
    } else {
        out[base + 32 + (l - 32)] = softplusf_(accq) + MINSTD;
        out[base + 128 + (l - 32)] = softplusf_(accp) + MINSTD;
    }
    if (t + 1 >= TT) return;
    int first1 = isf[row * TT + t + 1] > 0;
    float* a_s = aux + w * 40;
    if (l < STOCHN) a_s[l] = first1 ? sinit[l] : accq;
    else if (l < CATPI) a_s[l] = first1 ? 0.f : action[((size_t)row * TT + t + 1) * ACTN + (l - 32)];
    if (first1) {
        float dv[8];
        *(f32x4*)&dv[0] = *(const f32x4*)(dinit + j0);
        *(f32x4*)&dv[4] = *(const f32x4*)(dinit + j0 + 4);
        *(f32x4*)(deter + (size_t)row * 512 + j0) = *(const f32x4*)&dv[0];
        *(f32x4*)(deter + (size_t)row * 512 + j0 + 4) = *(const f32x4*)&dv[4];
        short8 db;
#pragma unroll
        for (int e = 0; e < 8; ++e) db[e] = f2b(dv[e]);
        *(short8*)(dbf + (size_t)row * 512 + j0) = db;
    }
    prior_in_row(row, l, a_s, Wpibf, g_pi, b_pi, xbf);
}

// ==== the persistent kernel (plain launch; grid=256 <= CU count => co-resident) ====
__global__ __launch_bounds__(256) void k_world(
    unsigned* cnt, const int* isf, const float* action, const __hip_bfloat16* Wpibf, const float* g_pi,
    const float* b_pi, const __hip_bfloat16* WgT, const float* g_gru, const float* b_gru,
    const __hip_bfloat16* WpoT, const float* g_po, const float* b_po, const __hip_bfloat16* WpnT,
    const float* g_pn, const float* b_pn, const __hip_bfloat16* WpsT, const float* b_ps,
    const __hip_bfloat16* WptT, const float* b_pt, const float* init_deter, const float* W_po_f,
    const float* W_ps_f, float* deter, float* gates, float* dinit, float* sinit, __hip_bfloat16* xbf,
    __hip_bfloat16* dbf, const __hip_bfloat16* obsbf, float* out) {
    __shared__ __align__(16) char smem[49152];
    __shared__ float aux[264];
    unsigned gen = 0;
    int bid = blockIdx.x;
    float* hbuf = gates;  // alias: disjoint lifetimes within a step (barrier-separated)

    if (bid == 0) phase_init(init_deter, W_po_f, g_po, b_po, W_ps_f, b_ps, dinit, sinit, (float*)smem, aux);
    gbar(cnt, gen);
    phase_prior0(isf, action, sinit, dinit, deter, dbf, Wpibf, g_pi, b_pi, xbf, aux);
    gbar(cnt, gen);

    for (int t = 0; t < TT; ++t) {
        // P1: gates = cat(x, deter) @ W_gru.  256 tiles of 64x96 (NFC=3).
        {
            int bm = bid & 15, bn = bid >> 4;  // bn 0..15
            gemm_tile_db<3>(xbf, 512, 512, dbf, 512, WgT, 1024, bn * 96, gates, G3N, bm * 64, bn * 96, 16, smem);
        }
        gbar(cnt, gen);
        p2_update(t, gates, g_gru, b_gru, deter, dbf, out);
        gbar(cnt, gen);
        // P3: hbuf = [deter@W_po | cat(deter,obs_t)@W_pn].  256 tiles of 64x64 (NFC=2).
        {
            int bm = bid & 15, bn = bid >> 4;
            if (bn < 8)
                gemm_tile_db<2>(dbf, 512, 512, dbf, 512, WpoT, 512, bn * 64, hbuf, 1024, bm * 64, bn * 64, 8, smem);
            else
                gemm_tile_db<2>(dbf, 512, 512, obsbf + (size_t)t * OBSN, TT * OBSN, WpnT, 576, (bn - 8) * 64, hbuf,
                                1024, bm * 64, 512 + (bn - 8) * 64, 9, smem);
        }
        gbar(cnt, gen);
        p4_stats(t, hbuf, g_po, b_po, g_pn, b_pn, WpsT, b_ps, WptT, b_pt, isf, action, sinit, dinit, deter, dbf,
                 Wpibf, g_pi, b_pi, xbf, out, (float*)smem, aux);
        gbar(cnt, gen);
    }
}

// ---- prologue: transpose + fp32->bf16: dst[N][K] = src[K][N] ----
__global__ __launch_bounds__(256) void k_transpose_bf(const float* __restrict__ src,
                                                      __hip_bfloat16* __restrict__ dst, int K, int N) {
    __shared__ float tle[32][33];
    int nTK = K >> 5;
    int k0 = (blockIdx.x % nTK) * 32;
    int n0 = (blockIdx.x / nTK) * 32;
    int tx = threadIdx.x & 31, ty = threadIdx.x >> 5;
#pragma unroll
    for (int i = 0; i < 4; ++i) tle[ty + i * 8][tx] = src[(size_t)(k0 + ty + i * 8) * N + n0 + tx];
    __syncthreads();
#pragma unroll
    for (int i = 0; i < 4; ++i)
        dst[(size_t)(n0 + ty + i * 8) * K + k0 + tx] = __float2bfloat16(tle[tx][ty + i * 8]);
}

__global__ __launch_bounds__(256) void k_cvt_bf(const float* __restrict__ src, __hip_bfloat16* __restrict__ dst,
                                                int n) {
    for (int i = blockIdx.x * 256 + threadIdx.x; i < n; i += gridDim.x * 256) dst[i] = __float2bfloat16(src[i]);
}

extern "C" void kernel_launch(void* const* d_in, const int* in_sizes, int n_in, void* d_out, int out_size, void* d_ws,
                              size_t ws_size, hipStream_t stream) {
    const float* obs = (const float*)d_in[0];
    const float* action = (const float*)d_in[1];
    const int* is_first = (const int*)d_in[2];
    const float* W_pi = (const float*)d_in[3];
    const float* g_pi = (const float*)d_in[4];
    const float* b_pi = (const float*)d_in[5];
    const float* W_gru = (const float*)d_in[6];
    const float* g_gru = (const float*)d_in[7];
    const float* b_gru = (const float*)d_in[8];
    const float* W_po = (const float*)d_in[9];
    const float* g_po = (const float*)d_in[10];
    const float* b_po = (const float*)d_in[11];
    const float* W_ps = (const float*)d_in[12];
    const float* b_ps = (const float*)d_in[13];
    const float* W_pn = (const float*)d_in[14];
    const float* g_pn = (const float*)d_in[15];
    const float* b_pn = (const float*)d_in[16];
    const float* W_pt = (const float*)d_in[17];
    const float* b_pt = (const float*)d_in[18];
    const float* init_deter = (const float*)d_in[19];
    float* out = (float*)d_out;

    char* p = (char*)d_ws;
    auto alloc = [&](size_t bytes) {
        char* r = p;
        p += (bytes + 255) & ~(size_t)255;
        return r;
    };
    unsigned* cnt = (unsigned*)alloc(256);
    float* deter = (float*)alloc((size_t)BB * 512 * 4);
    float* gates = (float*)alloc((size_t)BB * G3N * 4);  // hbuf aliases inside kernel
    float* dinit = (float*)alloc(512 * 4);
    float* sinit = (float*)alloc(64 * 4);
    __hip_bfloat16* xbf = (__hip_bfloat16*)alloc((size_t)BB * 512 * 2);
    __hip_bfloat16* dbf = (__hip_bfloat16*)alloc((size_t)BB * 512 * 2);
    __hip_bfloat16* obsbf = (__hip_bfloat16*)alloc((size_t)BB * TT * OBSN * 2);
    __hip_bfloat16* WgT = (__hip_bfloat16*)alloc((size_t)G3N * 1024 * 2);
    __hip_bfloat16* WpoT = (__hip_bfloat16*)alloc((size_t)512 * 512 * 2);
    __hip_bfloat16* WpnT = (__hip_bfloat16*)alloc((size_t)512 * 576 * 2);
    __hip_bfloat16* WpsT = (__hip_bfloat16*)alloc((size_t)64 * 512 * 2);
    __hip_bfloat16* WptT = (__hip_bfloat16*)alloc((size_t)64 * 512 * 2);
    __hip_bfloat16* Wpibf = (__hip_bfloat16*)alloc((size_t)CATPI * 512 * 2);

    hipMemsetAsync(cnt, 0, 256, stream);
    k_transpose_bf<<<(1024 / 32) * (G3N / 32), 256, 0, stream>>>(W_gru, WgT, 1024, G3N);
    k_transpose_bf<<<(512 / 32) * (512 / 32), 256, 0, stream>>>(W_po, WpoT, 512, 512);
    k_transpose_bf<<<(576 / 32) * (512 / 32), 256, 0, stream>>>(W_pn, WpnT, 576, 512);
    k_transpose_bf<<<(512 / 32) * (64 / 32), 256, 0, stream>>>(W_ps, WpsT, 512, 64);
    k_transpose_bf<<<(512 / 32) * (64 / 32), 256, 0, stream>>>(W_pt, WptT, 512, 64);
    k_cvt_bf<<<2048, 256, 0, stream>>>(obs, obsbf, BB * TT * OBSN);
    k_cvt_bf<<<80, 256, 0, stream>>>(W_pi, Wpibf, CATPI * 512);

    k_world<<<NBLK, 256, 0, stream>>>(cnt, is_first, action, Wpibf, g_pi, b_pi, WgT, g_gru, b_gru, WpoT, g_po, b_po,
                                      WpnT, g_pn, b_pn, WpsT, b_ps, WptT, b_pt, init_deter, W_po, W_ps, deter, gates,
                                      dinit, sinit, xbf, dbf, obsbf, out);
}

// Round 5
// 5372.073 us; speedup vs baseline: 1.6914x; 1.6914x over previous
//
#include <hip/hip_runtime.h>
#include <hip/hip_bf16.h>
#include <math.h>

#define BB 1024
#define TT 64
#define OBSN 64
#define ACTN 8
#define STOCHN 32
#define DETERN 512
#define HIDN 512
#define G3N 1536
#define CATPI 40
#define OUTC 672
#define LNEPS 1e-3f
#define MINSTD 0.1f
#define UPDBIAS -1.0f
#define NBLK 256

typedef __attribute__((ext_vector_type(8))) short short8;
typedef __attribute__((ext_vector_type(4))) short short4v;
typedef __attribute__((ext_vector_type(4))) float f32x4;
typedef __attribute__((ext_vector_type(2))) float f32x2;
typedef __attribute__((ext_vector_type(2))) unsigned long long ull2;

__device__ __forceinline__ float sigmoidf_(float x) { return 1.f / (1.f + expf(-x)); }
__device__ __forceinline__ float siluf_(float x) { return x / (1.f + expf(-x)); }
__device__ __forceinline__ float softplusf_(float x) { return (x > 20.f) ? x : log1pf(expf(x)); }

__device__ __forceinline__ float b2f(short u) {
    unsigned x = ((unsigned)(unsigned short)u) << 16;
    return __builtin_bit_cast(float, x);
}
__device__ __forceinline__ short f2b(float f) {
    __hip_bfloat16 h = __float2bfloat16(f);
    return __builtin_bit_cast(short, h);
}

// ---- agent-scope relaxed (sc-flagged) accesses: coherent across XCDs via memory-side LLC,
// ---- bypass the non-coherent L1/L2. NO cache-flush instructions are ever emitted.
__device__ __forceinline__ unsigned long long cld8(const void* p) {
    return __hip_atomic_load((const unsigned long long*)p, __ATOMIC_RELAXED, __HIP_MEMORY_SCOPE_AGENT);
}
__device__ __forceinline__ void cst8(void* p, unsigned long long v) {
    __hip_atomic_store((unsigned long long*)p, v, __ATOMIC_RELAXED, __HIP_MEMORY_SCOPE_AGENT);
}
__device__ __forceinline__ void cst4f(float* p, float v) {
    __hip_atomic_store(p, v, __ATOMIC_RELAXED, __HIP_MEMORY_SCOPE_AGENT);
}
__device__ __forceinline__ f32x2 u2f2(unsigned long long v) { return __builtin_bit_cast(f32x2, v); }

__device__ __forceinline__ void gload_lds16(const void* g, void* l) {
    __builtin_amdgcn_global_load_lds((const __attribute__((address_space(1))) void*)g,
                                     (__attribute__((address_space(3))) void*)l, 16, 0, 0);
}

__device__ __forceinline__ void wred2(float& a, float& b) {
#pragma unroll
    for (int off = 32; off; off >>= 1) {
        a += __shfl_xor(a, off);
        b += __shfl_xor(b, off);
    }
}
__device__ __forceinline__ void wred4(float& a, float& b, float& c, float& d) {
#pragma unroll
    for (int off = 32; off; off >>= 1) {
        a += __shfl_xor(a, off);
        b += __shfl_xor(b, off);
        c += __shfl_xor(c, off);
        d += __shfl_xor(d, off);
    }
}

// ---- grid barrier: NO threadfence (no wbl2/inv). __syncthreads drains vmcnt(0) ->
// this block's sc1 stores are at the coherence point before the add is visible.
__device__ __forceinline__ void gbar(unsigned* cnt, unsigned& gen) {
    __syncthreads();
    gen += NBLK;
    if (threadIdx.x == 0) {
        __hip_atomic_fetch_add(cnt, 1u, __ATOMIC_RELAXED, __HIP_MEMORY_SCOPE_AGENT);
        while (__hip_atomic_load(cnt, __ATOMIC_RELAXED, __HIP_MEMORY_SCOPE_AGENT) < gen)
            __builtin_amdgcn_s_sleep(1);
    }
    __syncthreads();
}

// ---- block-wide reduction (k_init prologue only) ----
template <int NV>
__device__ __forceinline__ void breduce(float* v, float* red, int nwaves) {
    __syncthreads();
#pragma unroll
    for (int off = 32; off > 0; off >>= 1)
#pragma unroll
        for (int q = 0; q < NV; ++q) v[q] += __shfl_down(v[q], off);
    int lane = threadIdx.x & 63, w = threadIdx.x >> 6;
    if (lane == 0)
        for (int q = 0; q < NV; ++q) red[w * NV + q] = v[q];
    __syncthreads();
    if ((int)threadIdx.x < NV) {
        float s = 0.f;
        for (int ww = 0; ww < nwaves; ++ww) s += red[ww * NV + threadIdx.x];
        red[nwaves * NV + threadIdx.x] = s;
    }
    __syncthreads();
#pragma unroll
    for (int q = 0; q < NV; ++q) v[q] = red[nwaves * NV + q];
}

// ==== MFMA GEMM tile core. BM=64, BN=32*NFC, BK=64. 4 waves 2x2.
// A (mutable activations): sc1 8B loads -> regs -> swizzled ds_write_b128 (reg-staged, pipelined).
// B (read-only weights): global_load_lds, normal cached path (L2-resident).
template <int NFC>
__device__ __forceinline__ void compute_tile(const char* smA, const char* smB, f32x4 (&acc)[2][NFC]) {
    int lane = threadIdx.x & 63, wid = threadIdx.x >> 6;
    int wr = wid >> 1, wc = wid & 1;
#pragma unroll
    for (int ks = 0; ks < 2; ++ks) {
        short8 af[2], bfr[NFC];
        int kslot = ks * 4 + (lane >> 4);
#pragma unroll
        for (int m = 0; m < 2; ++m) {
            int row = wr * 32 + m * 16 + (lane & 15);
            af[m] = *(const short8*)(smA + row * 128 + ((kslot ^ (row & 7)) << 4));
        }
#pragma unroll
        for (int n = 0; n < NFC; ++n) {
            int row = wc * (16 * NFC) + n * 16 + (lane & 15);
            bfr[n] = *(const short8*)(smB + row * 128 + ((kslot ^ (row & 7)) << 4));
        }
#pragma unroll
        for (int m = 0; m < 2; ++m)
#pragma unroll
            for (int n = 0; n < NFC; ++n)
                acc[m][n] = __builtin_amdgcn_mfma_f32_16x16x32_bf16(af[m], bfr[n], acc[m][n], 0, 0, 0);
    }
}

template <int NFC>
__device__ __forceinline__ void gemm_core(const __hip_bfloat16* A0, int ld0, int K0, const __hip_bfloat16* A1,
                                          int ld1, const __hip_bfloat16* Wt, int ldW, int wn0, float* C, int ldc,
                                          int cm0, int cn0, int nK, char* smem) {
    char* smA[2] = {smem, smem + 8192};
    char* smB[2] = {smem + 16384, smem + 16384 + NFC * 4096};
    const int tid = threadIdx.x, wid = tid >> 6, lane = tid & 63;
    const int arow = tid >> 2, as0 = (tid & 3) * 2;   // A: row 0..63, two 16B slots
    const int rseg = lane >> 3, slot = lane & 7;      // B mapping
    f32x4 acc[2][NFC] = {};
    unsigned long long ar[4];

    auto issueA = [&](int kt) {
        int k0 = kt * 64;
        const __hip_bfloat16* Ab;
        int ldA, kloc;
        if (k0 < K0) { Ab = A0; ldA = ld0; kloc = k0; }
        else { Ab = A1; ldA = ld1; kloc = k0 - K0; }
        const __hip_bfloat16* base = Ab + (size_t)(cm0 + arow) * ldA + kloc + as0 * 8;
        ar[0] = cld8(base);
        ar[1] = cld8(base + 4);
        ar[2] = cld8(base + 8);
        ar[3] = cld8(base + 12);
    };
    auto writeA = [&](char* dst) {
        char* rb = dst + arow * 128;
        *(ull2*)(rb + ((as0 ^ (arow & 7)) << 4)) = ull2{ar[0], ar[1]};
        *(ull2*)(rb + (((as0 + 1) ^ (arow & 7)) << 4)) = ull2{ar[2], ar[3]};
    };
    auto issueB = [&](int kt, char* dstB) {
        int k0 = kt * 64;
#pragma unroll
        for (int i = 0; i < NFC; ++i) {
            int seg = wid * NFC + i;
            int row = seg * 8 + rseg;
            int kk = k0 + ((slot ^ (row & 7)) << 3);
            gload_lds16(Wt + (size_t)(wn0 + row) * ldW + kk, dstB + seg * 1024);
        }
    };

    issueA(0);
    issueB(0, smB[0]);
    writeA(smA[0]);  // compiler waits for ar regs
    __syncthreads();
    int cur = 0;
    for (int kt = 0; kt < nK; ++kt) {
        if (kt + 1 < nK) {
            issueA(kt + 1);             // sc1 latency hides under compute
            issueB(kt + 1, smB[cur ^ 1]);
        }
        compute_tile<NFC>(smA[cur], smB[cur], acc);
        if (kt + 1 < nK) writeA(smA[cur ^ 1]);
        __syncthreads();
        cur ^= 1;
    }
    const int wr = wid >> 1, wc = wid & 1;
    int r0 = cm0 + wr * 32 + ((lane >> 4) << 2);
    int c0 = cn0 + wc * 16 * NFC + (lane & 15);
#pragma unroll
    for (int m = 0; m < 2; ++m)
#pragma unroll
        for (int n = 0; n < NFC; ++n)
#pragma unroll
            for (int i = 0; i < 4; ++i)
                cst4f(&C[(size_t)(r0 + m * 16 + i) * ldc + c0 + n * 16], acc[m][n][i]);
}

// ---- shared prior_in row routine: x = silu(LN(a_s @ W_pi)) -> xbf (sc1) ----
__device__ __forceinline__ void prior_in_row(int row, int l, const float* a_s, const __hip_bfloat16* Wpibf,
                                             const float* g_pi, const float* b_pi, __hip_bfloat16* xbf) {
    int j0 = l * 8;
    float o[8] = {0.f, 0.f, 0.f, 0.f, 0.f, 0.f, 0.f, 0.f};
    for (int k = 0; k < CATPI; ++k) {
        float a = a_s[k];
        short8 w8 = *(const short8*)(Wpibf + k * 512 + j0);
#pragma unroll
        for (int e = 0; e < 8; ++e) o[e] += a * b2f(w8[e]);
    }
    float s = 0.f, sq = 0.f;
#pragma unroll
    for (int e = 0; e < 8; ++e) {
        s += o[e];
        sq += o[e] * o[e];
    }
    wred2(s, sq);
    float m = s * (1.f / 512.f), iv = rsqrtf(sq * (1.f / 512.f) - m * m + LNEPS);
    short8 xo;
#pragma unroll
    for (int e = 0; e < 8; ++e) {
        float x = siluf_((o[e] - m) * iv * g_pi[j0 + e] + b_pi[j0 + e]);
        xo[e] = f2b(x);
    }
    ull2 u = __builtin_bit_cast(ull2, xo);
    cst8(xbf + (size_t)row * 512 + j0, u[0]);
    cst8(xbf + (size_t)row * 512 + j0 + 4, u[1]);
}

// ---- t=0: state init (deter -> block-private LDS) + prior_in ----
__device__ void phase_prior0(const int* isf, const float* action, const float* sinit, const float* dinit,
                             float* deter_lds, __hip_bfloat16* dbf, const __hip_bfloat16* Wpibf,
                             const float* g_pi, const float* b_pi, __hip_bfloat16* xbf, float* aux) {
    int w = threadIdx.x >> 6, l = threadIdx.x & 63;
    int row = blockIdx.x * 4 + w;
    float* a_s = aux + w * 40;
    int first = isf[row * TT] > 0;
    if (l < CATPI) a_s[l] = (l < STOCHN) ? sinit[l] : (first ? 0.f : action[(size_t)row * TT * ACTN + (l - 32)]);
    int j0 = l * 8;
    f32x4 d0 = *(const f32x4*)(dinit + j0);
    f32x4 d1 = *(const f32x4*)(dinit + j0 + 4);
    float* drow = deter_lds + w * 512;
    *(f32x4*)(drow + j0) = d0;
    *(f32x4*)(drow + j0 + 4) = d1;
    short8 db;
#pragma unroll
    for (int e = 0; e < 4; ++e) db[e] = f2b(d0[e]);
#pragma unroll
    for (int e = 0; e < 4; ++e) db[4 + e] = f2b(d1[e]);
    ull2 u = __builtin_bit_cast(ull2, db);
    cst8(dbf + (size_t)row * 512 + j0, u[0]);
    cst8(dbf + (size_t)row * 512 + j0 + 4, u[1]);
    prior_in_row(row, l, a_s, Wpibf, g_pi, b_pi, xbf);
}

// ---- P2: LN(gates) + GRU update -> deter (LDS) + dbf (sc1) + out ----
__device__ void p2_update(int t, const float* gates, const float* g_gru, const float* b_gru, float* deter_lds,
                          __hip_bfloat16* dbf, float* out) {
    int w = threadIdx.x >> 6, l = threadIdx.x & 63;
    int row = blockIdx.x * 4 + w;
    const float* gr = gates + (size_t)row * G3N;
    float gv[6][4];
    float s = 0.f, sq = 0.f;
#pragma unroll
    for (int i = 0; i < 6; ++i) {
        f32x2 a = u2f2(cld8(gr + i * 256 + l * 4));
        f32x2 b = u2f2(cld8(gr + i * 256 + l * 4 + 2));
        gv[i][0] = a[0];
        gv[i][1] = a[1];
        gv[i][2] = b[0];
        gv[i][3] = b[1];
#pragma unroll
        for (int c = 0; c < 4; ++c) {
            s += gv[i][c];
            sq += gv[i][c] * gv[i][c];
        }
    }
    wred2(s, sq);
    float m = s * (1.f / 1536.f), iv = rsqrtf(sq * (1.f / 1536.f) - m * m + LNEPS);
    size_t obase = ((size_t)row * TT + t) * OUTC + 160;
    float* drow = deter_lds + w * 512;
#pragma unroll
    for (int i = 0; i < 2; ++i) {
        int j = i * 256 + l * 4;
        f32x4 grr = *(const f32x4*)(g_gru + j), brr = *(const f32x4*)(b_gru + j);
        f32x4 gcc = *(const f32x4*)(g_gru + 512 + j), bcc = *(const f32x4*)(b_gru + 512 + j);
        f32x4 guu = *(const f32x4*)(g_gru + 1024 + j), buu = *(const f32x4*)(b_gru + 1024 + j);
        f32x4 dp = *(const f32x4*)(drow + j);
        f32x4 dn;
        short4v db;
#pragma unroll
        for (int c = 0; c < 4; ++c) {
            float rv = sigmoidf_((gv[i][c] - m) * iv * grr[c] + brr[c]);
            float cv = (gv[i + 2][c] - m) * iv * gcc[c] + bcc[c];
            float uv = sigmoidf_((gv[i + 4][c] - m) * iv * guu[c] + buu[c] + UPDBIAS);
            float cand = siluf_(rv * cv);
            dn[c] = uv * cand + (1.f - uv) * dp[c];
            db[c] = f2b(dn[c]);
        }
        *(f32x4*)(drow + j) = dn;
        *(f32x4*)(out + obase + j) = dn;  // normal store (write-only, flushed at kernel end)
        cst8(dbf + (size_t)row * 512 + j, __builtin_bit_cast(unsigned long long, db));
    }
}

// ---- P4: LN+silu hp/hq, stats dots, outputs, next-step state mask + prior_in ----
__device__ void p4_stats(int t, const float* hbuf, const float* g_po, const float* b_po, const float* g_pn,
                         const float* b_pn, const __hip_bfloat16* WpsT, const float* b_ps,
                         const __hip_bfloat16* WptT, const float* b_pt, const int* isf, const float* action,
                         const float* sinit, const float* dinit, float* deter_lds, __hip_bfloat16* dbf,
                         const __hip_bfloat16* Wpibf, const float* g_pi, const float* b_pi, __hip_bfloat16* xbf,
                         float* out, float* smemf, float* aux) {
    int w = threadIdx.x >> 6, l = threadIdx.x & 63;
    int row = blockIdx.x * 4 + w;
    float* hp_s = smemf + w * 512;
    float* hq_s = smemf + 2048 + w * 512;
    const float* hrow = hbuf + (size_t)row * 1024;
    int j0 = l * 8;
    float hp[8], hq[8];
#pragma unroll
    for (int q = 0; q < 4; ++q) {
        f32x2 a = u2f2(cld8(hrow + j0 + q * 2));
        f32x2 b = u2f2(cld8(hrow + 512 + j0 + q * 2));
        hp[q * 2] = a[0];
        hp[q * 2 + 1] = a[1];
        hq[q * 2] = b[0];
        hq[q * 2 + 1] = b[1];
    }
    float sp = 0.f, spq = 0.f, sh = 0.f, shq = 0.f;
#pragma unroll
    for (int e = 0; e < 8; ++e) {
        sp += hp[e];
        spq += hp[e] * hp[e];
        sh += hq[e];
        shq += hq[e] * hq[e];
    }
    wred4(sp, spq, sh, shq);
    float mp = sp * (1.f / 512.f), ip = rsqrtf(spq * (1.f / 512.f) - mp * mp + LNEPS);
    float mq = sh * (1.f / 512.f), iq = rsqrtf(shq * (1.f / 512.f) - mq * mq + LNEPS);
#pragma unroll
    for (int e = 0; e < 8; ++e) {
        hp[e] = siluf_((hp[e] - mp) * ip * g_po[j0 + e] + b_po[j0 + e]);
        hq[e] = siluf_((hq[e] - mq) * iq * g_pn[j0 + e] + b_pn[j0 + e]);
    }
    *(f32x4*)&hp_s[j0] = *(const f32x4*)&hp[0];
    *(f32x4*)&hp_s[j0 + 4] = *(const f32x4*)&hp[4];
    *(f32x4*)&hq_s[j0] = *(const f32x4*)&hq[0];
    *(f32x4*)&hq_s[j0 + 4] = *(const f32x4*)&hq[4];
    // stats dots: lane l computes ps[l] (from hp) and qs[l] (from hq); per-wave LDS region
    float accp = b_ps[l], accq = b_pt[l];
    const __hip_bfloat16* wpr = WpsT + (size_t)l * 512;
    const __hip_bfloat16* wqr = WptT + (size_t)l * 512;
    for (int k0 = 0; k0 < 512; k0 += 8) {
        short8 wp = *(const short8*)(wpr + k0);
        short8 wq = *(const short8*)(wqr + k0);
        float a[8], c[8];
        *(f32x4*)&a[0] = *(const f32x4*)&hp_s[k0];
        *(f32x4*)&a[4] = *(const f32x4*)&hp_s[k0 + 4];
        *(f32x4*)&c[0] = *(const f32x4*)&hq_s[k0];
        *(f32x4*)&c[4] = *(const f32x4*)&hq_s[k0 + 4];
#pragma unroll
        for (int e = 0; e < 8; ++e) {
            accp += b2f(wp[e]) * a[e];
            accq += b2f(wq[e]) * c[e];
        }
    }
    size_t base = ((size_t)row * TT + t) * OUTC;
    if (l < 32) {
        out[base + l] = accq;
        out[base + 64 + l] = accq;
        out[base + 96 + l] = accp;
    } else {
        out[base + 32 + (l - 32)] = softplusf_(accq) + MINSTD;
        out[base + 128 + (l - 32)] = softplusf_(accp) + MINSTD;
    }
    if (t + 1 >= TT) return;
    int first1 = isf[row * TT + t + 1] > 0;
    float* a_s = aux + w * 40;
    if (l < STOCHN) a_s[l] = first1 ? sinit[l] : accq;
    else if (l < CATPI) a_s[l] = first1 ? 0.f : action[((size_t)row * TT + t + 1) * ACTN + (l - 32)];
    if (first1) {
        f32x4 d0 = *(const f32x4*)(dinit + j0);
        f32x4 d1 = *(const f32x4*)(dinit + j0 + 4);
        float* drow = deter_lds + w * 512;
        *(f32x4*)(drow + j0) = d0;
        *(f32x4*)(drow + j0 + 4) = d1;
        short8 db;
#pragma unroll
        for (int e = 0; e < 4; ++e) db[e] = f2b(d0[e]);
#pragma unroll
        for (int e = 0; e < 4; ++e) db[4 + e] = f2b(d1[e]);
        ull2 u = __builtin_bit_cast(ull2, db);
        cst8(dbf + (size_t)row * 512 + j0, u[0]);
        cst8(dbf + (size_t)row * 512 + j0 + 4, u[1]);
    }
    prior_in_row(row, l, a_s, Wpibf, g_pi, b_pi, xbf);
}

// ==== persistent kernel (plain launch; grid=256 <= CU count => co-resident) ====
__global__ __launch_bounds__(256) void k_world(
    unsigned* cnt, const int* isf, const float* action, const __hip_bfloat16* Wpibf, const float* g_pi,
    const float* b_pi, const __hip_bfloat16* WgT, const float* g_gru, const float* b_gru,
    const __hip_bfloat16* WpoT, const float* g_po, const float* b_po, const __hip_bfloat16* WpnT,
    const float* g_pn, const float* b_pn, const __hip_bfloat16* WpsT, const float* b_ps,
    const __hip_bfloat16* WptT, const float* b_pt, const float* dinit, const float* sinit, float* gates,
    __hip_bfloat16* xbf, __hip_bfloat16* dbf, const __hip_bfloat16* obsbf, float* out) {
    __shared__ __align__(16) char smem[40960];
    __shared__ float deter_lds[2048];
    __shared__ float aux[160];
    unsigned gen = 0;
    int bid = blockIdx.x;
    float* hbuf = gates;  // alias: disjoint lifetimes (barrier-separated)

    phase_prior0(isf, action, sinit, dinit, deter_lds, dbf, Wpibf, g_pi, b_pi, xbf, aux);
    gbar(cnt, gen);

    for (int t = 0; t < TT; ++t) {
        // P1: gates = cat(x, deter) @ W_gru.  256 tiles: 16 bm x 16 bn of 64x96 (NFC=3).
        {
            int bm = bid & 15, bn = bid >> 4;
            gemm_core<3>(xbf, 512, 512, dbf, 512, WgT, 1024, bn * 96, gates, G3N, bm * 64, bn * 96, 16, smem);
        }
        gbar(cnt, gen);
        p2_update(t, gates, g_gru, b_gru, deter_lds, dbf, out);
        gbar(cnt, gen);
        // P3: hbuf = [deter@W_po | cat(deter,obs_t)@W_pn].  256 tiles of 64x64 (NFC=2).
        {
            int bm = bid & 15, bn = bid >> 4;
            if (bn < 8)
                gemm_core<2>(dbf, 512, 512, dbf, 512, WpoT, 512, bn * 64, hbuf, 1024, bm * 64, bn * 64, 8, smem);
            else
                gemm_core<2>(dbf, 512, 512, obsbf + (size_t)t * OBSN, TT * OBSN, WpnT, 576, (bn - 8) * 64, hbuf,
                             1024, bm * 64, 512 + (bn - 8) * 64, 9, smem);
        }
        gbar(cnt, gen);
        p4_stats(t, hbuf, g_po, b_po, g_pn, b_pn, WpsT, b_ps, WptT, b_pt, isf, action, sinit, dinit, deter_lds,
                 dbf, Wpibf, g_pi, b_pi, xbf, out, (float*)smem, aux);
        gbar(cnt, gen);
    }
}

// ---- prologue: d_init = tanh(init_deter); s_init = prior mean at d_init ----
__global__ __launch_bounds__(512) void k_init(const float* __restrict__ init_deter, const float* __restrict__ W_po,
                                              const float* __restrict__ g_po, const float* __restrict__ b_po,
                                              const float* __restrict__ W_ps, const float* __restrict__ b_ps,
                                              float* __restrict__ dinit, float* __restrict__ sinit) {
    __shared__ float d_s[512], h_s[512], red[40];
    int tid = threadIdx.x;
    float dv = tanhf(init_deter[tid]);
    d_s[tid] = dv;
    dinit[tid] = dv;
    __syncthreads();
    float acc = 0.f;
    for (int k = 0; k < 512; ++k) acc += d_s[k] * W_po[k * 512 + tid];
    float v[2] = {acc, acc * acc};
    breduce<2>(v, red, 8);
    float m = v[0] / 512.f, va = v[1] / 512.f - m * m, iv = rsqrtf(va + LNEPS);
    h_s[tid] = siluf_((acc - m) * iv * g_po[tid] + b_po[tid]);
    __syncthreads();
    if (tid < 32) {
        float s = b_ps[tid];
        for (int k = 0; k < 512; ++k) s += h_s[k] * W_ps[k * 64 + tid];
        sinit[tid] = s;
    }
}

// ---- prologue: transpose + fp32->bf16: dst[N][K] = src[K][N] ----
__global__ __launch_bounds__(256) void k_transpose_bf(const float* __restrict__ src,
                                                      __hip_bfloat16* __restrict__ dst, int K, int N) {
    __shared__ float tle[32][33];
    int nTK = K >> 5;
    int k0 = (blockIdx.x % nTK) * 32;
    int n0 = (blockIdx.x / nTK) * 32;
    int tx = threadIdx.x & 31, ty = threadIdx.x >> 5;
#pragma unroll
    for (int i = 0; i < 4; ++i) tle[ty + i * 8][tx] = src[(size_t)(k0 + ty + i * 8) * N + n0 + tx];
    __syncthreads();
#pragma unroll
    for (int i = 0; i < 4; ++i)
        dst[(size_t)(n0 + ty + i * 8) * K + k0 + tx] = __float2bfloat16(tle[tx][ty + i * 8]);
}

__global__ __launch_bounds__(256) void k_cvt_bf(const float* __restrict__ src, __hip_bfloat16* __restrict__ dst,
                                                int n) {
    for (int i = blockIdx.x * 256 + threadIdx.x; i < n; i += gridDim.x * 256) dst[i] = __float2bfloat16(src[i]);
}

extern "C" void kernel_launch(void* const* d_in, const int* in_sizes, int n_in, void* d_out, int out_size, void* d_ws,
                              size_t ws_size, hipStream_t stream) {
    const float* obs = (const float*)d_in[0];
    const float* action = (const float*)d_in[1];
    const int* is_first = (const int*)d_in[2];
    const float* W_pi = (const float*)d_in[3];
    const float* g_pi = (const float*)d_in[4];
    const float* b_pi = (const float*)d_in[5];
    const float* W_gru = (const float*)d_in[6];
    const float* g_gru = (const float*)d_in[7];
    const float* b_gru = (const float*)d_in[8];
    const float* W_po = (const float*)d_in[9];
    const float* g_po = (const float*)d_in[10];
    const float* b_po = (const float*)d_in[11];
    const float* W_ps = (const float*)d_in[12];
    const float* b_ps = (const float*)d_in[13];
    const float* W_pn = (const float*)d_in[14];
    const float* g_pn = (const float*)d_in[15];
    const float* b_pn = (const float*)d_in[16];
    const float* W_pt = (const float*)d_in[17];
    const float* b_pt = (const float*)d_in[18];
    const float* init_deter = (const float*)d_in[19];
    float* out = (float*)d_out;

    char* p = (char*)d_ws;
    auto alloc = [&](size_t bytes) {
        char* r = p;
        p += (bytes + 255) & ~(size_t)255;
        return r;
    };
    unsigned* cnt = (unsigned*)alloc(256);
    float* gates = (float*)alloc((size_t)BB * G3N * 4);  // hbuf aliases inside kernel
    float* dinit = (float*)alloc(512 * 4);
    float* sinit = (float*)alloc(64 * 4);
    __hip_bfloat16* xbf = (__hip_bfloat16*)alloc((size_t)BB * 512 * 2);
    __hip_bfloat16* dbf = (__hip_bfloat16*)alloc((size_t)BB * 512 * 2);
    __hip_bfloat16* obsbf = (__hip_bfloat16*)alloc((size_t)BB * TT * OBSN * 2);
    __hip_bfloat16* WgT = (__hip_bfloat16*)alloc((size_t)G3N * 1024 * 2);
    __hip_bfloat16* WpoT = (__hip_bfloat16*)alloc((size_t)512 * 512 * 2);
    __hip_bfloat16* WpnT = (__hip_bfloat16*)alloc((size_t)512 * 576 * 2);
    __hip_bfloat16* WpsT = (__hip_bfloat16*)alloc((size_t)64 * 512 * 2);
    __hip_bfloat16* WptT = (__hip_bfloat16*)alloc((size_t)64 * 512 * 2);
    __hip_bfloat16* Wpibf = (__hip_bfloat16*)alloc((size_t)CATPI * 512 * 2);

    hipMemsetAsync(cnt, 0, 256, stream);
    k_transpose_bf<<<(1024 / 32) * (G3N / 32), 256, 0, stream>>>(W_gru, WgT, 1024, G3N);
    k_transpose_bf<<<(512 / 32) * (512 / 32), 256, 0, stream>>>(W_po, WpoT, 512, 512);
    k_transpose_bf<<<(576 / 32) * (512 / 32), 256, 0, stream>>>(W_pn, WpnT, 576, 512);
    k_transpose_bf<<<(512 / 32) * (64 / 32), 256, 0, stream>>>(W_ps, WpsT, 512, 64);
    k_transpose_bf<<<(512 / 32) * (64 / 32), 256, 0, stream>>>(W_pt, WptT, 512, 64);
    k_cvt_bf<<<2048, 256, 0, stream>>>(obs, obsbf, BB * TT * OBSN);
    k_cvt_bf<<<80, 256, 0, stream>>>(W_pi, Wpibf, CATPI * 512);
    k_init<<<1, 512, 0, stream>>>(init_deter, W_po, g_po, b_po, W_ps, b_ps, dinit, sinit);

    k_world<<<NBLK, 256, 0, stream>>>(cnt, is_first, action, Wpibf, g_pi, b_pi, WgT, g_gru, b_gru, WpoT, g_po, b_po,
                                      WpnT, g_pn, b_pn, WpsT, b_ps, WptT, b_pt, dinit, sinit, gates, xbf, dbf,
                                      obsbf, out);
}